// Round 13
// baseline (103.815 us; speedup 1.0000x reference)
//
#include <hip/hip_runtime.h>
#include <float.h>

#define N_SRC 20000
#define N_TAR 20000
#define TPB 512                    // 8 waves/block
#define SPLITS 16                  // source splits (grid.y)
#define TILES 40                   // 32-source tiles per split; 16*1280 = 20480 >= 20000
#define TGRP 40                    // target groups (grid.x): 40 blocks * 512 targets = 20480
#define FBLOCKS ((N_TAR + 255) / 256)

typedef _Float16 half8 __attribute__((ext_vector_type(8)));
typedef float floatx16 __attribute__((ext_vector_type(16)));

// q(t,s) = 0.5||s||^2 - t.s, so 0.5*d2 = 0.5||t||^2 + q. (r12-verified numerics:
// split-f16 cross terms in K=16 slots of mfma_f32_32x32x16_f16, absmax 0.)
// r13 changes, attacking the CU LDS pipe (r12's hidden bottleneck):
//  - 2 strips (64 targets) per wave: each ds_read_b128 of B feeds 4 MFMAs
//  - DPP cross-lane min epilogue (VALU pipe) replaces 80 ds_swizzle shfls
//  - v_min3 tile-pairing halves the min-VALU pass

// cross-lane min over the 32 cols of each 32-lane half, result in lanes 16-31
// (and 48-63). quad_perm xor1, xor2, half-mirror, row-mirror, then bcast15.
#define DPP_MIN(v, ctrl) { \
    const int _s = __builtin_amdgcn_update_dpp( \
        __float_as_int(v), __float_as_int(v), (ctrl), 0xf, 0xf, false); \
    v = fminf(v, __int_as_float(_s)); }
#define COL_REDUCE(v) { \
    DPP_MIN(v, 0xB1)  /* quad_perm [1,0,3,2] : xor1 */ \
    DPP_MIN(v, 0x4E)  /* quad_perm [2,3,0,1] : xor2 */ \
    DPP_MIN(v, 0x141) /* row_half_mirror     : 8-group */ \
    DPP_MIN(v, 0x140) /* row_mirror          : 16-row  */ \
    DPP_MIN(v, 0x142) /* row_bcast15 -> lanes 16-31 hold the 32-col min */ }

__global__
__attribute__((amdgpu_flat_work_group_size(TPB, TPB)))
__attribute__((amdgpu_waves_per_eu(4)))
void nn_mfma(
    const float* __restrict__ src, const float* __restrict__ tar,
    float* __restrict__ part, float* __restrict__ out)
{
    if (blockIdx.x == 0 && blockIdx.y == 0 && threadIdx.x == 0) out[0] = 0.f;

    __shared__ alignas(16) _Float16 lds[TILES * 512];  // 40 KB

    const int tid  = threadIdx.x;
    const int lane = tid & 63;
    const int col  = lane & 31;
    const int half = (lane >> 5) & 1;
    const int wave = tid >> 6;

    // ---- stage B fragments for this split's 1280 sources ----
    const int sbase = blockIdx.y * (TILES * 32);
    for (int ls = tid; ls < TILES * 32; ls += TPB) {
        const int s = sbase + ls;
        half8 f0 = {0, 0, 0, 0, 0, 0, 0, 0};
        half8 f1 = {0, 0, 0, 0, 0, 0, 0, 0};
        if (s < N_SRC) {
            const float x = src[s * 3 + 0];
            const float y = src[s * 3 + 1];
            const float z = src[s * 3 + 2];
            const _Float16 xh = (_Float16)x, yh = (_Float16)y, zh = (_Float16)z;
            const _Float16 xl = (_Float16)(x - (float)xh);
            const _Float16 yl = (_Float16)(y - (float)yh);
            const _Float16 zl = (_Float16)(z - (float)zh);
            const float nrm = 0.5f * (x * x + y * y + z * z);
            const _Float16 nh = (_Float16)nrm;
            const _Float16 nl = (_Float16)(nrm - (float)nh);
            f0 = (half8){xh, yh, zh, xh, yh, zh, xl, yl};
            f1 = (half8){zl, nh, nl, 0, 0, 0, 0, 0};
        } else {
            f1 = (half8){0, (_Float16)30000.f, 0, 0, 0, 0, 0, 0}; // never the min
        }
        *(half8*)&lds[ls * 16 + 0] = f0;
        *(half8*)&lds[ls * 16 + 8] = f1;
    }

    // ---- A fragments: this wave's 2 strips of 32 targets ----
    const int strip0 = (blockIdx.x * 8 + wave) * 2;
    half8 a0, a1;
#pragma unroll
    for (int sidx = 0; sidx < 2; ++sidx) {
        const int t = min((strip0 + sidx) * 32 + col, N_TAR - 1);
        const float tx = tar[t * 3 + 0];
        const float ty = tar[t * 3 + 1];
        const float tz = tar[t * 3 + 2];
        const _Float16 txh = (_Float16)tx, tyh = (_Float16)ty, tzh = (_Float16)tz;
        const _Float16 txl = (_Float16)(tx - (float)txh);
        const _Float16 tyl = (_Float16)(ty - (float)tyh);
        const _Float16 tzl = (_Float16)(tz - (float)tzh);
        half8 a;
        if (half == 0)
            a = (half8){-txh, -tyh, -tzh, -txl, -tyl, -tzl, -txh, -tyh};
        else
            a = (half8){-tzh, (_Float16)1.f, (_Float16)1.f, 0, 0, 0, 0, 0};
        if (sidx == 0) a0 = a; else a1 = a;
    }

    __syncthreads();

    // ---- tile loop: 2 ds_read_b128 + 4 mfma + 32 v_min3 per 2 tiles ----
    floatx16 m0, m1;
#pragma unroll
    for (int i = 0; i < 16; ++i) { m0[i] = FLT_MAX; m1[i] = FLT_MAX; }
    const floatx16 zero = {};
    const int foff = col * 16 + half * 8;

    half8 b0 = *(const half8*)&lds[0 * 512 + foff];
    half8 b1 = *(const half8*)&lds[1 * 512 + foff];
#pragma unroll 2
    for (int tp = 0; tp < TILES; tp += 2) {
        const int nx = min(tp + 2, TILES - 2);   // clamped prefetch (dup ok under min)
        const half8 n0 = *(const half8*)&lds[nx * 512 + foff];
        const half8 n1 = *(const half8*)&lds[(nx + 1) * 512 + foff];
        const floatx16 d00 = __builtin_amdgcn_mfma_f32_32x32x16_f16(a0, b0, zero, 0, 0, 0);
        const floatx16 d01 = __builtin_amdgcn_mfma_f32_32x32x16_f16(a0, b1, zero, 0, 0, 0);
        const floatx16 d10 = __builtin_amdgcn_mfma_f32_32x32x16_f16(a1, b0, zero, 0, 0, 0);
        const floatx16 d11 = __builtin_amdgcn_mfma_f32_32x32x16_f16(a1, b1, zero, 0, 0, 0);
#pragma unroll
        for (int i = 0; i < 16; ++i) {
            m0[i] = fminf(m0[i], fminf(d00[i], d01[i]));   // -> v_min3_f32
            m1[i] = fminf(m1[i], fminf(d10[i], d11[i]));
        }
        b0 = n0; b1 = n1;
    }

    // ---- DPP column reduction (no DS ops), store from lanes 16 / 48 ----
#pragma unroll
    for (int i = 0; i < 16; ++i) { COL_REDUCE(m0[i]) COL_REDUCE(m1[i]) }

    if (col == 16) {
        float* prow = part + (size_t)blockIdx.y * N_TAR;
#pragma unroll
        for (int i = 0; i < 16; ++i) {
            const int row = (i & 3) + 8 * (i >> 2) + 4 * half;
            const int t0 = min(strip0 * 32 + row, N_TAR - 1);
            const int t1 = min((strip0 + 1) * 32 + row, N_TAR - 1);
            prow[t0] = m0[i];
            prow[t1] = m1[i];
        }
    }
}

// combine the SPLITS mins per target, add 0.5||t||^2, reduce into out[0]
__global__ __launch_bounds__(256) void nn_finalize(
    const float* __restrict__ tar, const float* __restrict__ part,
    float* __restrict__ out)
{
    const int t = blockIdx.x * 256 + threadIdx.x;
    float contrib = 0.f;
    if (t < N_TAR) {
        float m = FLT_MAX;
#pragma unroll
        for (int c = 0; c < SPLITS; ++c) m = fminf(m, part[c * N_TAR + t]);
        const float tx = tar[t * 3 + 0];
        const float ty = tar[t * 3 + 1];
        const float tz = tar[t * 3 + 2];
        contrib = 0.5f * (tx * tx + ty * ty + tz * tz) + m;
    }
    for (int off = 32; off > 0; off >>= 1)
        contrib += __shfl_down(contrib, off);
    __shared__ float red[4];
    if ((threadIdx.x & 63) == 0) red[threadIdx.x >> 6] = contrib;
    __syncthreads();
    if (threadIdx.x == 0) {
        float s = 0.f;
#pragma unroll
        for (int w = 0; w < 4; ++w) s += red[w];
        atomicAdd(out, s);
    }
}

extern "C" void kernel_launch(void* const* d_in, const int* in_sizes, int n_in,
                              void* d_out, int out_size, void* d_ws, size_t ws_size,
                              hipStream_t stream) {
    const float* src = (const float*)d_in[0];  // [20000,3] fp32
    const float* tar = (const float*)d_in[1];  // [20000,3] fp32
    float* out = (float*)d_out;                // scalar fp32
    float* part = (float*)d_ws;                // SPLITS * N_TAR floats = 1.28 MB

    dim3 grid1(TGRP, SPLITS);
    nn_mfma<<<grid1, TPB, 0, stream>>>(src, tar, part, out);
    nn_finalize<<<FBLOCKS, 256, 0, stream>>>(tar, part, out);
}

// Round 14
// 94.234 us; speedup vs baseline: 1.1017x; 1.1017x over previous
//
#include <hip/hip_runtime.h>
#include <float.h>

#define N_SRC 20000
#define N_TAR 20000
#define TPB 256                    // 4 waves/block
#define SPLITS 12                  // source splits (grid.y)
#define TILES 54                   // 32-source tiles per split; 12*54*32 = 20736 >= 20000
#define SRC_PAD (SPLITS * TILES * 32)      // 20736 pack entries
#define TGRP 79                    // 79 blocks * 4 waves * 2 strips * 32 = 20224 targets
#define TAR_PAD (TGRP * TPB)       // 20224 apack entries
#define FBLOCKS ((N_TAR + 255) / 256)

typedef _Float16 half8 __attribute__((ext_vector_type(8)));
typedef float floatx16 __attribute__((ext_vector_type(16)));

// q(t,s) = 0.5||s||^2 - t.s, so 0.5*d2 = 0.5||t||^2 + q. (r12-verified split-f16
// numerics in K=16 slots of mfma_f32_32x32x16_f16; absmax 0.)
// r14: LDS removed from the hot kernel (r13: 1.02e6 bank-conflict cycles +
// staging barrier). A/B fragments precomputed ONCE by nn_prep into global
// (pack 663 KB, apack 647 KB -> L2-resident), read coalesced as dwordx4.

// ---- DPP column-min (VALU pipe only; r13-verified, absmax 0) ----
#define DPP_MIN(v, ctrl) { \
    const int _s = __builtin_amdgcn_update_dpp( \
        __float_as_int(v), __float_as_int(v), (ctrl), 0xf, 0xf, false); \
    v = fminf(v, __int_as_float(_s)); }
#define COL_REDUCE(v) { \
    DPP_MIN(v, 0xB1)  /* quad_perm xor1 */ \
    DPP_MIN(v, 0x4E)  /* quad_perm xor2 */ \
    DPP_MIN(v, 0x141) /* row_half_mirror */ \
    DPP_MIN(v, 0x140) /* row_mirror */ \
    DPP_MIN(v, 0x142) /* row_bcast15 -> lanes 16-31 hold the 32-col min */ }

// prep: pack[i] (two half8 per source i), apack[i] (two half8 per target i),
// zero out[0]. 81 blocks x 256 = 20736 threads.
__global__ __launch_bounds__(TPB) void nn_prep(
    const float* __restrict__ src, const float* __restrict__ tar,
    half8* __restrict__ pack, half8* __restrict__ apack,
    float* __restrict__ out)
{
    const int i = blockIdx.x * TPB + threadIdx.x;
    if (i == 0) out[0] = 0.f;

    if (i < SRC_PAD) {
        half8 f0 = {0, 0, 0, 0, 0, 0, 0, 0};
        half8 f1 = {0, (_Float16)30000.f, 0, 0, 0, 0, 0, 0};  // pad: never the min
        if (i < N_SRC) {
            const float x = src[i * 3 + 0];
            const float y = src[i * 3 + 1];
            const float z = src[i * 3 + 2];
            const _Float16 xh = (_Float16)x, yh = (_Float16)y, zh = (_Float16)z;
            const _Float16 xl = (_Float16)(x - (float)xh);
            const _Float16 yl = (_Float16)(y - (float)yh);
            const _Float16 zl = (_Float16)(z - (float)zh);
            const float nrm = 0.5f * (x * x + y * y + z * z);
            const _Float16 nh = (_Float16)nrm;
            const _Float16 nl = (_Float16)(nrm - (float)nh);
            f0 = (half8){xh, yh, zh, xh, yh, zh, xl, yl};
            f1 = (half8){zl, nh, nl, 0, 0, 0, 0, 0};
        }
        pack[i * 2 + 0] = f0;
        pack[i * 2 + 1] = f1;
    }

    if (i < TAR_PAD) {
        const int t = min(i, N_TAR - 1);
        const float tx = tar[t * 3 + 0];
        const float ty = tar[t * 3 + 1];
        const float tz = tar[t * 3 + 2];
        const _Float16 txh = (_Float16)tx, tyh = (_Float16)ty, tzh = (_Float16)tz;
        const _Float16 txl = (_Float16)(tx - (float)txh);
        const _Float16 tyl = (_Float16)(ty - (float)tyh);
        const _Float16 tzl = (_Float16)(tz - (float)tzh);
        apack[i * 2 + 0] = (half8){-txh, -tyh, -tzh, -txl, -tyl, -tzl, -txh, -tyh};
        apack[i * 2 + 1] = (half8){-tzh, (_Float16)1.f, (_Float16)1.f, 0, 0, 0, 0, 0};
    }
}

// main: no LDS, no barriers. Per tile-pair: 2 coalesced global b128 loads
// (L2) + 4 mfma + 32 v_min3, with one-pair register prefetch.
__global__ __launch_bounds__(TPB) void nn_mfma(
    const half8* __restrict__ pack, const half8* __restrict__ apack,
    float* __restrict__ part)
{
    const int tid  = threadIdx.x;
    const int lane = tid & 63;
    const int col  = lane & 31;
    const int half = (lane >> 5) & 1;
    const int wave = tid >> 6;

    // A fragments: this wave's 2 strips of 32 targets (coalesced b128 reads)
    const int strip0 = (blockIdx.x * 4 + wave) * 2;
    const half8 a0 = apack[strip0 * 64 + col * 2 + half];
    const half8 a1 = apack[(strip0 + 1) * 64 + col * 2 + half];

    // B walk: entry(tile) = (sbase + tile*32 + col)*2 + half
    const int sbase = blockIdx.y * (TILES * 32);
    const half8* bp = pack + (size_t)(sbase + col) * 2 + half;
    // tile stride in entries: 32*2 = 64

    floatx16 m0, m1;
#pragma unroll
    for (int i = 0; i < 16; ++i) { m0[i] = FLT_MAX; m1[i] = FLT_MAX; }
    const floatx16 zero = {};

    half8 b0 = bp[0];
    half8 b1 = bp[64];
#pragma unroll 1
    for (int tp = 0; tp < TILES; tp += 2) {
        const int nx = min(tp + 2, TILES - 2);   // clamped prefetch (dup load ok)
        const half8 n0 = bp[nx * 64];
        const half8 n1 = bp[nx * 64 + 64];
        const floatx16 d00 = __builtin_amdgcn_mfma_f32_32x32x16_f16(a0, b0, zero, 0, 0, 0);
        const floatx16 d01 = __builtin_amdgcn_mfma_f32_32x32x16_f16(a0, b1, zero, 0, 0, 0);
        const floatx16 d10 = __builtin_amdgcn_mfma_f32_32x32x16_f16(a1, b0, zero, 0, 0, 0);
        const floatx16 d11 = __builtin_amdgcn_mfma_f32_32x32x16_f16(a1, b1, zero, 0, 0, 0);
#pragma unroll
        for (int i = 0; i < 16; ++i) {
            m0[i] = fminf(m0[i], fminf(d00[i], d01[i]));   // v_min3_f32
            m1[i] = fminf(m1[i], fminf(d10[i], d11[i]));
        }
        b0 = n0; b1 = n1;
    }

#pragma unroll
    for (int i = 0; i < 16; ++i) { COL_REDUCE(m0[i]) COL_REDUCE(m1[i]) }

    if (col == 16) {
        float* prow = part + (size_t)blockIdx.y * N_TAR;
#pragma unroll
        for (int i = 0; i < 16; ++i) {
            const int row = (i & 3) + 8 * (i >> 2) + 4 * half;
            const int t0 = min(strip0 * 32 + row, N_TAR - 1);
            const int t1 = min((strip0 + 1) * 32 + row, N_TAR - 1);
            prow[t0] = m0[i];   // clamped rows rewrite identical values: benign
            prow[t1] = m1[i];
        }
    }
}

// combine the SPLITS mins per target, add 0.5||t||^2, reduce into out[0]
__global__ __launch_bounds__(256) void nn_finalize(
    const float* __restrict__ tar, const float* __restrict__ part,
    float* __restrict__ out)
{
    const int t = blockIdx.x * 256 + threadIdx.x;
    float contrib = 0.f;
    if (t < N_TAR) {
        float m = FLT_MAX;
#pragma unroll
        for (int c = 0; c < SPLITS; ++c) m = fminf(m, part[c * N_TAR + t]);
        const float tx = tar[t * 3 + 0];
        const float ty = tar[t * 3 + 1];
        const float tz = tar[t * 3 + 2];
        contrib = 0.5f * (tx * tx + ty * ty + tz * tz) + m;
    }
    for (int off = 32; off > 0; off >>= 1)
        contrib += __shfl_down(contrib, off);
    __shared__ float red[4];
    if ((threadIdx.x & 63) == 0) red[threadIdx.x >> 6] = contrib;
    __syncthreads();
    if (threadIdx.x == 0) {
        float s = 0.f;
#pragma unroll
        for (int w = 0; w < 4; ++w) s += red[w];
        atomicAdd(out, s);
    }
}

extern "C" void kernel_launch(void* const* d_in, const int* in_sizes, int n_in,
                              void* d_out, int out_size, void* d_ws, size_t ws_size,
                              hipStream_t stream) {
    const float* src = (const float*)d_in[0];  // [20000,3] fp32
    const float* tar = (const float*)d_in[1];  // [20000,3] fp32
    float* out = (float*)d_out;                // scalar fp32

    // workspace carve-up (all rewritten every call; harness poisons ws)
    char* w = (char*)d_ws;
    float* part  = (float*)w;                              //  960 KB
    half8* pack  = (half8*)(w + 1024 * 1024);              //  663 KB
    half8* apack = (half8*)(w + 2 * 1024 * 1024);          //  647 KB

    nn_prep<<<(SRC_PAD + TPB - 1) / TPB, TPB, 0, stream>>>(src, tar, pack, apack, out);
    dim3 grid1(TGRP, SPLITS);
    nn_mfma<<<grid1, TPB, 0, stream>>>(pack, apack, part);
    nn_finalize<<<FBLOCKS, 256, 0, stream>>>(tar, part, out);
}

// Round 15
// 79.490 us; speedup vs baseline: 1.3060x; 1.1855x over previous
//
#include <hip/hip_runtime.h>
#include <float.h>

#define N_SRC 20000
#define N_TAR 20000
#define TPB 256                    // 4 waves/block
#define SPLITS 12                  // source splits (grid.y)
#define TILES 54                   // 32-source tiles per split; 12*54*32 = 20736 >= 20000
#define SRC_PAD (SPLITS * TILES * 32)      // 20736 pack entries
#define TGRP 79                    // 79 blocks * 4 waves * 2 strips * 32 = 20224 targets
#define TAR_PAD (TGRP * TPB)       // 20224 apack entries
#define FBLOCKS ((N_TAR + 255) / 256)

typedef _Float16 half8 __attribute__((ext_vector_type(8)));
typedef float floatx16 __attribute__((ext_vector_type(16)));

// q(t,s) = 0.5||s||^2 - t.s, so 0.5*d2 = 0.5||t||^2 + q. (r12-verified split-f16
// numerics in K=16 slots of mfma_f32_32x32x16_f16; absmax 0 in r12/r13/r14.)
// r15 vs r14 (inferred nn_mfma ~40us vs ~10us floor -> L2-latency exposed at
// prefetch depth 1 with 64 live d-regs):
//  - prefetch ring depth 4 tiles (~500 cyc coverage vs ~250 cyc L2 latency)
//  - d-sets consumed pairwise (32 live regs, not 64)
//  - __launch_bounds__(256,4): <=128 VGPR -> 4 waves/SIMD, 948 blocks fully
//    resident in one round (capacity 1024)

#define DPP_MIN(v, ctrl) { \
    const int _s = __builtin_amdgcn_update_dpp( \
        __float_as_int(v), __float_as_int(v), (ctrl), 0xf, 0xf, false); \
    v = fminf(v, __int_as_float(_s)); }
#define COL_REDUCE(v) { \
    DPP_MIN(v, 0xB1)  /* quad_perm xor1 */ \
    DPP_MIN(v, 0x4E)  /* quad_perm xor2 */ \
    DPP_MIN(v, 0x141) /* row_half_mirror */ \
    DPP_MIN(v, 0x140) /* row_mirror */ \
    DPP_MIN(v, 0x142) /* row_bcast15 -> lanes 16-31 hold the 32-col min */ }

// prep: pack[i] (two half8 per source), apack[i] (two half8 per target), zero out.
__global__ __launch_bounds__(TPB) void nn_prep(
    const float* __restrict__ src, const float* __restrict__ tar,
    half8* __restrict__ pack, half8* __restrict__ apack,
    float* __restrict__ out)
{
    const int i = blockIdx.x * TPB + threadIdx.x;
    if (i == 0) out[0] = 0.f;

    if (i < SRC_PAD) {
        half8 f0 = {0, 0, 0, 0, 0, 0, 0, 0};
        half8 f1 = {0, (_Float16)30000.f, 0, 0, 0, 0, 0, 0};  // pad: never the min
        if (i < N_SRC) {
            const float x = src[i * 3 + 0];
            const float y = src[i * 3 + 1];
            const float z = src[i * 3 + 2];
            const _Float16 xh = (_Float16)x, yh = (_Float16)y, zh = (_Float16)z;
            const _Float16 xl = (_Float16)(x - (float)xh);
            const _Float16 yl = (_Float16)(y - (float)yh);
            const _Float16 zl = (_Float16)(z - (float)zh);
            const float nrm = 0.5f * (x * x + y * y + z * z);
            const _Float16 nh = (_Float16)nrm;
            const _Float16 nl = (_Float16)(nrm - (float)nh);
            f0 = (half8){xh, yh, zh, xh, yh, zh, xl, yl};
            f1 = (half8){zl, nh, nl, 0, 0, 0, 0, 0};
        }
        pack[i * 2 + 0] = f0;
        pack[i * 2 + 1] = f1;
    }

    if (i < TAR_PAD) {
        const int t = min(i, N_TAR - 1);
        const float tx = tar[t * 3 + 0];
        const float ty = tar[t * 3 + 1];
        const float tz = tar[t * 3 + 2];
        const _Float16 txh = (_Float16)tx, tyh = (_Float16)ty, tzh = (_Float16)tz;
        const _Float16 txl = (_Float16)(tx - (float)txh);
        const _Float16 tyl = (_Float16)(ty - (float)tyh);
        const _Float16 tzl = (_Float16)(tz - (float)tzh);
        apack[i * 2 + 0] = (half8){-txh, -tyh, -tzh, -txl, -tyl, -tzl, -txh, -tyh};
        apack[i * 2 + 1] = (half8){-tzh, (_Float16)1.f, (_Float16)1.f, 0, 0, 0, 0, 0};
    }
}

// main: no LDS, no barriers. Ring of 4 prefetched B tiles; per tile-pair:
// 4 mfma consumed pairwise + 32 v_min3 + 2 coalesced b128 L2 loads.
__global__ __launch_bounds__(TPB, 4) void nn_mfma(
    const half8* __restrict__ pack, const half8* __restrict__ apack,
    float* __restrict__ part)
{
    const int tid  = threadIdx.x;
    const int lane = tid & 63;
    const int col  = lane & 31;
    const int half = (lane >> 5) & 1;
    const int wave = tid >> 6;

    const int strip0 = (blockIdx.x * 4 + wave) * 2;
    const half8 a0 = apack[strip0 * 64 + col * 2 + half];
    const half8 a1 = apack[(strip0 + 1) * 64 + col * 2 + half];

    // B walk: entry(tile) = (sbase + tile*32 + col)*2 + half; tile stride = 64
    const int sbase = blockIdx.y * (TILES * 32);
    const half8* bp = pack + (size_t)(sbase + col) * 2 + half;

    floatx16 m0, m1;
#pragma unroll
    for (int i = 0; i < 16; ++i) { m0[i] = FLT_MAX; m1[i] = FLT_MAX; }
    const floatx16 zero = {};

    // prefetch ring: 4 tiles in flight
    half8 r0 = bp[0 * 64];
    half8 r1 = bp[1 * 64];
    half8 r2 = bp[2 * 64];
    half8 r3 = bp[3 * 64];
#pragma unroll 1
    for (int tp = 0; tp < TILES; tp += 2) {
        const int nx = min(tp + 4, TILES - 2);   // clamped (dup load ok under min)
        const half8 n0 = bp[nx * 64];
        const half8 n1 = bp[nx * 64 + 64];
        // pairwise consumption keeps only 2 d-sets (32 regs) live at once
        {
            const floatx16 d00 = __builtin_amdgcn_mfma_f32_32x32x16_f16(a0, r0, zero, 0, 0, 0);
            const floatx16 d01 = __builtin_amdgcn_mfma_f32_32x32x16_f16(a0, r1, zero, 0, 0, 0);
#pragma unroll
            for (int i = 0; i < 16; ++i) m0[i] = fminf(m0[i], fminf(d00[i], d01[i]));
        }
        {
            const floatx16 d10 = __builtin_amdgcn_mfma_f32_32x32x16_f16(a1, r0, zero, 0, 0, 0);
            const floatx16 d11 = __builtin_amdgcn_mfma_f32_32x32x16_f16(a1, r1, zero, 0, 0, 0);
#pragma unroll
            for (int i = 0; i < 16; ++i) m1[i] = fminf(m1[i], fminf(d10[i], d11[i]));
        }
        r0 = r2; r1 = r3; r2 = n0; r3 = n1;
    }

#pragma unroll
    for (int i = 0; i < 16; ++i) { COL_REDUCE(m0[i]) COL_REDUCE(m1[i]) }

    if (col == 16) {
        float* prow = part + (size_t)blockIdx.y * N_TAR;
#pragma unroll
        for (int i = 0; i < 16; ++i) {
            const int row = (i & 3) + 8 * (i >> 2) + 4 * half;
            const int t0 = min(strip0 * 32 + row, N_TAR - 1);
            const int t1 = min((strip0 + 1) * 32 + row, N_TAR - 1);
            prow[t0] = m0[i];   // clamped rows rewrite identical values: benign
            prow[t1] = m1[i];
        }
    }
}

// combine the SPLITS mins per target, add 0.5||t||^2, reduce into out[0]
__global__ __launch_bounds__(256) void nn_finalize(
    const float* __restrict__ tar, const float* __restrict__ part,
    float* __restrict__ out)
{
    const int t = blockIdx.x * 256 + threadIdx.x;
    float contrib = 0.f;
    if (t < N_TAR) {
        float m = FLT_MAX;
#pragma unroll
        for (int c = 0; c < SPLITS; ++c) m = fminf(m, part[c * N_TAR + t]);
        const float tx = tar[t * 3 + 0];
        const float ty = tar[t * 3 + 1];
        const float tz = tar[t * 3 + 2];
        contrib = 0.5f * (tx * tx + ty * ty + tz * tz) + m;
    }
    for (int off = 32; off > 0; off >>= 1)
        contrib += __shfl_down(contrib, off);
    __shared__ float red[4];
    if ((threadIdx.x & 63) == 0) red[threadIdx.x >> 6] = contrib;
    __syncthreads();
    if (threadIdx.x == 0) {
        float s = 0.f;
#pragma unroll
        for (int w = 0; w < 4; ++w) s += red[w];
        atomicAdd(out, s);
    }
}

extern "C" void kernel_launch(void* const* d_in, const int* in_sizes, int n_in,
                              void* d_out, int out_size, void* d_ws, size_t ws_size,
                              hipStream_t stream) {
    const float* src = (const float*)d_in[0];  // [20000,3] fp32
    const float* tar = (const float*)d_in[1];  // [20000,3] fp32
    float* out = (float*)d_out;                // scalar fp32

    char* w = (char*)d_ws;
    float* part  = (float*)w;                              //  960 KB
    half8* pack  = (half8*)(w + 1024 * 1024);              //  663 KB
    half8* apack = (half8*)(w + 2 * 1024 * 1024);          //  647 KB

    nn_prep<<<(SRC_PAD + TPB - 1) / TPB, TPB, 0, stream>>>(src, tar, pack, apack, out);
    dim3 grid1(TGRP, SPLITS);
    nn_mfma<<<grid1, TPB, 0, stream>>>(pack, apack, part);
    nn_finalize<<<FBLOCKS, 256, 0, stream>>>(tar, part, out);
}